// Round 2
// baseline (426.890 us; speedup 1.0000x reference)
//
#include <hip/hip_runtime.h>
#include <math.h>

#define DIM 1024
#define NH 16
#define HD 64
#define BATCH 4
#define SEQ 4096
#define NTOK (BATCH*SEQ)  // 16384

typedef float f32x4 __attribute__((ext_vector_type(4)));
typedef short bf16x8 __attribute__((ext_vector_type(8)));

// LDS dest must be WAVE-UNIFORM base; HW writes base + lane*16B.
#define GLOAD_LDS16(gp, lp)                                                    \
  __builtin_amdgcn_global_load_lds(                                            \
      (const __attribute__((address_space(1))) unsigned int*)(gp),             \
      (__attribute__((address_space(3))) unsigned int*)(lp), 16, 0, 0)

__device__ __forceinline__ unsigned short f2bf(float f) {
  unsigned u = __float_as_uint(f);
  unsigned r = (u + 0x7fffu + ((u >> 16) & 1u)) >> 16;
  return (unsigned short)r;
}
__device__ __forceinline__ float bf2f(unsigned short s) {
  return __uint_as_float((unsigned)s << 16);
}

// ---------------------------------------------------------------------------
// 256x256 bf16 GEMM, m201-template rhythm in plain HIP.
//   C = A[16384,1024] @ B[NT_N*256,1024]^T + bias
// 512 threads = 8 waves (2M x 4N), per-wave 128x64 out (8x4 16x16 frags).
// K-loop FULLY UNROLLED (32 K-halves of 32 cols): LDS slots are
// compile-time constants -> compiler can alias-disambiguate ds_read vs
// outstanding global_load_lds and emit COUNTED waits, not vmcnt(0).
// Rhythm (2 barriers per K-half, every region = MFMA ∥ stage ∥ next-reads):
//   ... bar | MFMA1(h) ; stageB(h+3) ; read a2(h) ; vmcnt(8) | bar |
//       MFMA2(h) ; stageA(h+4) ; read bb(h+1),a1(h+1)        | bar ...
// The MFMA->next-reads edge is BARRIER-FREE: reads issue+drain under the
// other wave's MFMA cluster (the read∥MFMA overlap m196 isolated).
// vmcnt(8): 12 stage-instrs in flight (3 K-halves deep), drain oldest 4
// -> slot h+1 ready; never 0 in steady state (T4). setprio around MFMA (T5).
// Chunk-XOR swizzle (proven 0-conflict): row r's k-chunk c at LDS chunk
// c^((r>>1)&3); read phase fq = (q8^((fr>>1)&3))*8 -> 2-way = free.
// ---------------------------------------------------------------------------
template <int NT_N, int OUT_BF16>
__global__ __launch_bounds__(512, 2) void gemm256(
    const unsigned short* __restrict__ A,
    const unsigned short* __restrict__ B,
    const float* __restrict__ b0, const float* __restrict__ b1,
    const float* __restrict__ b2,
    void* __restrict__ C0, void* __restrict__ C1, void* __restrict__ C2)
{
    __shared__ unsigned short SA[4][8192];   // 4 slots x 256x32 bf16 = 64KB
    __shared__ unsigned short SB[4][8192];   // 64KB  (total 128KB)
    const int t    = threadIdx.x;
    const int lane = t & 63;
    const int w    = t >> 6;

    // bijective XCD swizzle (nwg % 8 == 0 for both grids)
    const int cpx = gridDim.x >> 3;
    const int swz = (blockIdx.x & 7) * cpx + (blockIdx.x >> 3);
    const int mi  = swz / NT_N;
    const int ni  = swz % NT_N;
    const int m0  = mi * 256;
    const int n0g = ni * 256;                    // row into concat B

    const int wm = (w >> 2) * 128;
    const int wn = (w & 3) * 64;

    // staging: thread t -> row t>>2 (+128*j), global k-seg (t&3)^((t>>3)&3)
    // stored at LDS chunk t&3   [(t>>3)&3 == (row>>1)&3, j-independent]
    const int srow = t >> 2;
    const int sseg = ((t & 3) ^ ((t >> 3) & 3)) * 8;
    const unsigned short* Ag = A + (size_t)(m0 + srow) * 1024 + sseg;
    const unsigned short* Bg = B + (size_t)(n0g + srow) * 1024 + sseg;
    const int ldst = w * 512;                    // wave-uniform LDS base

    // fragment read: row fr's k-chunk q8 sits at LDS chunk q8^((fr>>1)&3)
    const int fr = lane & 15;
    const int fq = ((lane >> 4) ^ ((fr >> 1) & 3)) * 8;

    f32x4 acc[8][4] = {};
    bf16x8 a1[4], a2[4], bb[2][4];

#define STGA(k, j)                                                            \
  GLOAD_LDS16(Ag + (size_t)(j) * 131072 + (size_t)(k) * 32,                   \
              &SA[(k) & 3][(j) * 4096 + ldst])
#define STGB(k, j)                                                            \
  GLOAD_LDS16(Bg + (size_t)(j) * 131072 + (size_t)(k) * 32,                   \
              &SB[(k) & 3][(j) * 4096 + ldst])
#define VMW_(N) asm volatile("s_waitcnt vmcnt(" #N ")" ::: "memory")
#define VMW(N) VMW_(N)
#define MEMFENCE asm volatile("" ::: "memory")
#define BARRIER                                                               \
  __builtin_amdgcn_s_barrier();                                               \
  __builtin_amdgcn_sched_barrier(0)

#define BODY(h, VM)                                                           \
  {                                                                           \
    __builtin_amdgcn_s_setprio(1);                                            \
    _Pragma("unroll")                                                         \
    for (int mf = 0; mf < 4; ++mf)                                            \
      _Pragma("unroll")                                                       \
      for (int nf = 0; nf < 4; ++nf)                                          \
        acc[mf][nf] = __builtin_amdgcn_mfma_f32_16x16x32_bf16(                \
            a1[mf], bb[(h) & 1][nf], acc[mf][nf], 0, 0, 0);                   \
    __builtin_amdgcn_s_setprio(0);                                            \
    if ((h) <= 28) { STGB((h) + 3, 0); STGB((h) + 3, 1); }                    \
    _Pragma("unroll")                                                         \
    for (int mf = 0; mf < 4; ++mf)                                            \
      a2[mf] = *(const bf16x8*)                                               \
          &SA[(h) & 3][(wm + 64 + mf * 16 + fr) * 32 + fq];                   \
    VMW(VM);                                                                  \
    BARRIER;                                                                  \
    __builtin_amdgcn_s_setprio(1);                                            \
    _Pragma("unroll")                                                         \
    for (int mf = 0; mf < 4; ++mf)                                            \
      _Pragma("unroll")                                                       \
      for (int nf = 0; nf < 4; ++nf)                                          \
        acc[4 + mf][nf] = __builtin_amdgcn_mfma_f32_16x16x32_bf16(            \
            a2[mf], bb[(h) & 1][nf], acc[4 + mf][nf], 0, 0, 0);               \
    __builtin_amdgcn_s_setprio(0);                                            \
    if ((h) <= 27) { STGA((h) + 4, 0); STGA((h) + 4, 1); }                    \
    _Pragma("unroll")                                                         \
    for (int nf = 0; nf < 4; ++nf)                                            \
      bb[((h) + 1) & 1][nf] = *(const bf16x8*)                                \
          &SB[((h) + 1) & 3][(wn + nf * 16 + fr) * 32 + fq];                  \
    _Pragma("unroll")                                                         \
    for (int mf = 0; mf < 4; ++mf)                                            \
      a1[mf] = *(const bf16x8*)                                               \
          &SA[((h) + 1) & 3][(wm + mf * 16 + fr) * 32 + fq];                  \
    MEMFENCE;                                                                 \
    BARRIER;                                                                  \
  }

    // ---- prologue: stage K-halves 0,1,2 (12 loads in flight) ----
    STGA(0, 0); STGA(0, 1); STGB(0, 0); STGB(0, 1);
    STGA(1, 0); STGA(1, 1); STGB(1, 0); STGB(1, 1);
    STGA(2, 0); STGA(2, 1); STGB(2, 0); STGB(2, 1);
    VMW(8);               // slot 0 landed
    BARRIER;
    STGA(3, 0); STGA(3, 1);
#pragma unroll
    for (int nf = 0; nf < 4; ++nf)
        bb[0][nf] = *(const bf16x8*)&SB[0][(wn + nf * 16 + fr) * 32 + fq];
#pragma unroll
    for (int mf = 0; mf < 4; ++mf)
        a1[mf] = *(const bf16x8*)&SA[0][(wm + mf * 16 + fr) * 32 + fq];
    MEMFENCE;
    BARRIER;

    // ---- main: K-halves 0..30, fully unrolled, compile-time slots ----
    BODY(0, 8)  BODY(1, 8)  BODY(2, 8)  BODY(3, 8)  BODY(4, 8)
    BODY(5, 8)  BODY(6, 8)  BODY(7, 8)  BODY(8, 8)  BODY(9, 8)
    BODY(10, 8) BODY(11, 8) BODY(12, 8) BODY(13, 8) BODY(14, 8)
    BODY(15, 8) BODY(16, 8) BODY(17, 8) BODY(18, 8) BODY(19, 8)
    BODY(20, 8) BODY(21, 8) BODY(22, 8) BODY(23, 8) BODY(24, 8)
    BODY(25, 8) BODY(26, 8) BODY(27, 8) BODY(28, 8)
    BODY(29, 4) BODY(30, 0)

    // ---- tail: K-half 31 (slot 3, bb bank 1), no barriers needed ----
    __builtin_amdgcn_s_setprio(1);
#pragma unroll
    for (int mf = 0; mf < 4; ++mf)
#pragma unroll
        for (int nf = 0; nf < 4; ++nf)
            acc[mf][nf] = __builtin_amdgcn_mfma_f32_16x16x32_bf16(
                a1[mf], bb[1][nf], acc[mf][nf], 0, 0, 0);
    __builtin_amdgcn_s_setprio(0);
#pragma unroll
    for (int mf = 0; mf < 4; ++mf)
        a2[mf] = *(const bf16x8*)&SA[3][(wm + 64 + mf * 16 + fr) * 32 + fq];
    __builtin_amdgcn_s_setprio(1);
#pragma unroll
    for (int mf = 0; mf < 4; ++mf)
#pragma unroll
        for (int nf = 0; nf < 4; ++nf)
            acc[4 + mf][nf] = __builtin_amdgcn_mfma_f32_16x16x32_bf16(
                a2[mf], bb[1][nf], acc[4 + mf][nf], 0, 0, 0);
    __builtin_amdgcn_s_setprio(0);

#undef BODY
#undef BARRIER
#undef MEMFENCE
#undef VMW
#undef VMW_
#undef STGB
#undef STGA

    // epilogue: matrix select (uniform per block); C/D layout col=lane&15,
    // row=(lane>>4)*4+r
    const int mat = ni >> 2;
    const float* bias = (mat == 0) ? b0 : (mat == 1) ? b1 : b2;
    void* Cp = (mat == 0) ? C0 : (mat == 1) ? C1 : C2;
    const int n0 = (ni & 3) * 256;

    const int col = lane & 15;
    const int rq  = (lane >> 4) * 4;
#pragma unroll
    for (int nf = 0; nf < 4; ++nf) {
        int cbase = n0 + wn + nf * 16 + col;
        float bv = bias[cbase];
#pragma unroll
        for (int mf = 0; mf < 8; ++mf) {
            int rbase = m0 + wm + (mf >> 2) * 64 + (mf & 3) * 16 + rq;
#pragma unroll
            for (int r = 0; r < 4; ++r) {
                float val = acc[mf][nf][r] + bv;
                size_t idx = (size_t)(rbase + r) * 1024 + cbase;
                if (OUT_BF16)
                    ((unsigned short*)Cp)[idx] = f2bf(val);
                else
                    ((float*)Cp)[idx] = val;
            }
        }
    }
}

// ---------------------------------------------------------------------------
// fp32 -> bf16 casts
// ---------------------------------------------------------------------------
__global__ __launch_bounds__(256) void cast_bf16(
    const float* __restrict__ src, unsigned short* __restrict__ dst, int n)
{
    int i = (blockIdx.x * 256 + threadIdx.x) * 4;
    if (i >= n) return;
    float4 v = *(const float4*)&src[i];
    ushort2 lo = {f2bf(v.x), f2bf(v.y)};
    ushort2 hi = {f2bf(v.z), f2bf(v.w)};
    *(ushort2*)&dst[i] = lo;
    *(ushort2*)&dst[i + 2] = hi;
}

__global__ __launch_bounds__(256) void cast_bf16_w4(
    const float* __restrict__ s0, const float* __restrict__ s1,
    const float* __restrict__ s2, const float* __restrict__ s3,
    unsigned short* __restrict__ d0, unsigned short* __restrict__ d1,
    unsigned short* __restrict__ d2, unsigned short* __restrict__ d3)
{
    const float* s = (blockIdx.y == 0) ? s0 : (blockIdx.y == 1) ? s1
                    : (blockIdx.y == 2) ? s2 : s3;
    unsigned short* d = (blockIdx.y == 0) ? d0 : (blockIdx.y == 1) ? d1
                       : (blockIdx.y == 2) ? d2 : d3;
    int i = (blockIdx.x * 256 + threadIdx.x) * 4;
    float4 v = *(const float4*)&s[i];
    ushort2 lo = {f2bf(v.x), f2bf(v.y)};
    ushort2 hi = {f2bf(v.z), f2bf(v.w)};
    *(ushort2*)&d[i] = lo;
    *(ushort2*)&d[i + 2] = hi;
}

// ---------------------------------------------------------------------------
// MFMA Performer feature map, in place on bf16 rows of 64.
// ---------------------------------------------------------------------------
__global__ __launch_bounds__(256) void featmap_mfma(
    unsigned short* __restrict__ buf, const float* __restrict__ R)
{
    __shared__ unsigned short Rt[64 * 72];
    const int t = threadIdx.x;
    for (int i = t; i < 4096; i += 256) {
        int n = i >> 6, k = i & 63;
        Rt[n * 72 + k] = f2bf(R[k * 64 + n]);
    }
    __syncthreads();

    const int lane = t & 63;
    const int w = t >> 6;
    const size_t rowbase = (size_t)blockIdx.x * 256 + w * 64;
    const int fr = lane & 15;
    const int fq = (lane >> 4) * 8;

    f32x4 acc[4][4] = {};
    float sqacc[4] = {0.f, 0.f, 0.f, 0.f};

#pragma unroll
    for (int ks = 0; ks < 2; ks++) {
        bf16x8 bfr[4];
#pragma unroll
        for (int nt = 0; nt < 4; nt++)
            bfr[nt] = *(const bf16x8*)&Rt[(nt * 16 + fr) * 72 + ks * 32 + fq];
#pragma unroll
        for (int mt = 0; mt < 4; mt++) {
            bf16x8 a = *(const bf16x8*)
                &buf[(rowbase + mt * 16 + fr) * 64 + ks * 32 + fq];
#pragma unroll
            for (int j = 0; j < 8; j++) {
                float v = bf2f((unsigned short)a[j]);
                sqacc[mt] = fmaf(v, v, sqacc[mt]);
            }
#pragma unroll
            for (int nt = 0; nt < 4; nt++)
                acc[mt][nt] = __builtin_amdgcn_mfma_f32_16x16x32_bf16(
                    a, bfr[nt], acc[mt][nt], 0, 0, 0);
        }
    }
#pragma unroll
    for (int mt = 0; mt < 4; mt++) {
        sqacc[mt] += __shfl_xor(sqacc[mt], 16);
        sqacc[mt] += __shfl_xor(sqacc[mt], 32);
    }

    const int col = lane & 15;
    const int rq  = (lane >> 4) * 4;
#pragma unroll
    for (int mt = 0; mt < 4; mt++) {
#pragma unroll
        for (int r = 0; r < 4; r++) {
            float s = __shfl(sqacc[mt], rq + r);
            size_t row = rowbase + mt * 16 + rq + r;
#pragma unroll
            for (int nt = 0; nt < 4; nt++) {
                float val = acc[mt][nt][r] * 0.125f - s * 0.0078125f;
                buf[row * 64 + nt * 16 + col] = f2bf(__expf(val));
            }
        }
    }
}

// ---------------------------------------------------------------------------
// kv[b,h,m,e] += sum_n k'[n,m] * v[n,e] over a 512-token chunk. bf16 in.
// ---------------------------------------------------------------------------
__global__ __launch_bounds__(256) void kv_accum(
    const unsigned short* __restrict__ kp, const unsigned short* __restrict__ vp,
    float* __restrict__ kv)
{
    __shared__ float Ks[16][68];
    __shared__ float Vs[16][68];
    const int chunk = blockIdx.x;
    const int h = blockIdx.y;
    const int b = blockIdx.z;
    const int t = threadIdx.x;
    const int tx = t & 15, ty = t >> 4;
    float c[4][4] = {};
    const int nbase = b * SEQ + chunk * 512;
    const int nl = t >> 4, seg = t & 15;
    for (int n0 = 0; n0 < 512; n0 += 16) {
        size_t gaddr = (size_t)(nbase + n0 + nl) * DIM + h * 64 + seg * 4;
        ushort4 kq = *(const ushort4*)&kp[gaddr];
        ushort4 vq = *(const ushort4*)&vp[gaddr];
        Ks[nl][seg * 4 + 0] = bf2f(kq.x); Ks[nl][seg * 4 + 1] = bf2f(kq.y);
        Ks[nl][seg * 4 + 2] = bf2f(kq.z); Ks[nl][seg * 4 + 3] = bf2f(kq.w);
        Vs[nl][seg * 4 + 0] = bf2f(vq.x); Vs[nl][seg * 4 + 1] = bf2f(vq.y);
        Vs[nl][seg * 4 + 2] = bf2f(vq.z); Vs[nl][seg * 4 + 3] = bf2f(vq.w);
        __syncthreads();
#pragma unroll
        for (int nn = 0; nn < 16; nn++) {
            float4 a = *(const float4*)&Ks[nn][ty * 4];
            float4 bq = *(const float4*)&Vs[nn][tx * 4];
            float aa[4] = {a.x, a.y, a.z, a.w};
            float bb[4] = {bq.x, bq.y, bq.z, bq.w};
#pragma unroll
            for (int i = 0; i < 4; i++)
#pragma unroll
                for (int j = 0; j < 4; j++)
                    c[i][j] += aa[i] * bb[j];
        }
        __syncthreads();
    }
    float* dst = &kv[(size_t)(b * NH + h) * 64 * 64];
#pragma unroll
    for (int i = 0; i < 4; i++)
#pragma unroll
        for (int j = 0; j < 4; j++)
            atomicAdd(&dst[(ty * 4 + i) * 64 + tx * 4 + j], c[i][j]);
}

// ---------------------------------------------------------------------------
// MFMA attn out: per (b,h), out[n,e] = z[n] * (q'[n,:] @ kv[:,e])
// ---------------------------------------------------------------------------
__global__ __launch_bounds__(256) void attn_out_mfma(
    const unsigned short* __restrict__ qp, const float* __restrict__ kv,
    unsigned short* __restrict__ ob)
{
    __shared__ unsigned short kvT[64 * 72];
    const int t = threadIdx.x;
    const int bh = blockIdx.y;
    const int b = bh >> 4, h = bh & 15;
    const float* kvp = &kv[(size_t)bh * 4096];
    for (int i = t; i < 4096; i += 256) {
        int m = i >> 6, e = i & 63;
        kvT[e * 72 + m] = f2bf(kvp[i]);
    }
    __syncthreads();

    const int lane = t & 63;
    const int w = t >> 6;
    const int rowInSeq = blockIdx.x * 256 + w * 64;
    const int fr = lane & 15;
    const int fq = (lane >> 4) * 8;

    f32x4 acc[4][4] = {};
    float rsum[4] = {0.f, 0.f, 0.f, 0.f};

#pragma unroll
    for (int ks = 0; ks < 2; ks++) {
        bf16x8 bfr[4];
#pragma unroll
        for (int nt = 0; nt < 4; nt++)
            bfr[nt] = *(const bf16x8*)&kvT[(nt * 16 + fr) * 72 + ks * 32 + fq];
#pragma unroll
        for (int mt = 0; mt < 4; mt++) {
            size_t n = (size_t)(b * SEQ + rowInSeq + mt * 16 + fr);
            bf16x8 a = *(const bf16x8*)&qp[n * DIM + h * 64 + ks * 32 + fq];
#pragma unroll
            for (int j = 0; j < 8; j++)
                rsum[mt] += bf2f((unsigned short)a[j]);
#pragma unroll
            for (int nt = 0; nt < 4; nt++)
                acc[mt][nt] = __builtin_amdgcn_mfma_f32_16x16x32_bf16(
                    a, bfr[nt], acc[mt][nt], 0, 0, 0);
        }
    }
#pragma unroll
    for (int mt = 0; mt < 4; mt++) {
        rsum[mt] += __shfl_xor(rsum[mt], 16);
        rsum[mt] += __shfl_xor(rsum[mt], 32);
    }

    const int col = lane & 15;
    const int rq  = (lane >> 4) * 4;
#pragma unroll
    for (int mt = 0; mt < 4; mt++) {
#pragma unroll
        for (int r = 0; r < 4; r++) {
            float s = __shfl(rsum[mt], rq + r);
            float z = 1.f / (s + 1e-8f);
            size_t n = (size_t)(b * SEQ + rowInSeq + mt * 16 + rq + r);
#pragma unroll
            for (int nt = 0; nt < 4; nt++)
                ob[n * DIM + h * 64 + nt * 16 + col] = f2bf(acc[mt][nt][r] * z);
        }
    }
}

extern "C" void kernel_launch(void* const* d_in, const int* in_sizes, int n_in,
                              void* d_out, int out_size, void* d_ws, size_t ws_size,
                              hipStream_t stream) {
    const float* x  = (const float*)d_in[0];
    const float* Wq = (const float*)d_in[1];
    const float* bq = (const float*)d_in[2];
    const float* Wk = (const float*)d_in[3];
    const float* bk = (const float*)d_in[4];
    const float* Wv = (const float*)d_in[5];
    const float* bv = (const float*)d_in[6];
    const float* Wo = (const float*)d_in[7];
    const float* bo = (const float*)d_in[8];
    const float* R  = (const float*)d_in[9];
    float* out = (float*)d_out;

    // workspace — 137 MB. qb/kb contiguous (featmap spans both).
    char* p = (char*)d_ws;
    unsigned short* xb = (unsigned short*)p; p += (size_t)NTOK * DIM * 2;  // 32MB
    unsigned short* qb = (unsigned short*)p; p += (size_t)NTOK * DIM * 2;  // 32MB
    unsigned short* kb = (unsigned short*)p; p += (size_t)NTOK * DIM * 2;  // 32MB
    unsigned short* vb = (unsigned short*)p; p += (size_t)NTOK * DIM * 2;  // 32MB
    float* kvb = (float*)p;                  p += (size_t)BATCH * NH * HD * HD * 4; // 1MB
    unsigned short* wqkv = (unsigned short*)p; p += (size_t)3 * DIM * DIM * 2; // 6MB contig
    unsigned short* wob  = (unsigned short*)p; p += (size_t)DIM * DIM * 2;     // 2MB

    hipMemsetAsync(kvb, 0, (size_t)BATCH * NH * HD * HD * sizeof(float), stream);

    cast_bf16<<<NTOK * DIM / (256 * 4), 256, 0, stream>>>(x, xb, NTOK * DIM);
    cast_bf16_w4<<<dim3(DIM * DIM / (256 * 4), 4), 256, 0, stream>>>(
        Wq, Wk, Wv, Wo,
        wqkv, wqkv + (size_t)DIM * DIM, wqkv + (size_t)2 * DIM * DIM, wob);

    // fused QKV projection: 64 m-tiles x 12 n-tiles = 768 blocks, 512 thr
    gemm256<12, 1><<<768, 512, 0, stream>>>(
        xb, wqkv, bq, bk, bv, qb, kb, vb);

    // feature map over q' and k' in one launch (contiguous rows)
    featmap_mfma<<<2 * NTOK * NH / 256, 256, 0, stream>>>(qb, R);

    kv_accum<<<dim3(8, NH, BATCH), 256, 0, stream>>>(kb, vb, kvb);

    // attn output reuses xb
    attn_out_mfma<<<dim3(SEQ / 256, BATCH * NH), 256, 0, stream>>>(qb, kvb, xb);

    // output projection: 64 x 4 = 256 blocks, fp32 out
    gemm256<4, 0><<<256, 512, 0, stream>>>(
        xb, wob, bo, bo, bo, out, out, out);
}

// Round 3
// 419.004 us; speedup vs baseline: 1.0188x; 1.0188x over previous
//
#include <hip/hip_runtime.h>
#include <math.h>

#define DIM 1024
#define NH 16
#define HD 64
#define BATCH 4
#define SEQ 4096
#define NTOK (BATCH*SEQ)  // 16384

typedef float f32x4 __attribute__((ext_vector_type(4)));
typedef short bf16x8 __attribute__((ext_vector_type(8)));

// LDS dest must be WAVE-UNIFORM base; HW writes base + lane*16B.
#define GLOAD_LDS16(gp, lp)                                                    \
  __builtin_amdgcn_global_load_lds(                                            \
      (const __attribute__((address_space(1))) unsigned int*)(gp),             \
      (__attribute__((address_space(3))) unsigned int*)(lp), 16, 0, 0)

__device__ __forceinline__ unsigned short f2bf(float f) {
  unsigned u = __float_as_uint(f);
  unsigned r = (u + 0x7fffu + ((u >> 16) & 1u)) >> 16;
  return (unsigned short)r;
}
__device__ __forceinline__ float bf2f(unsigned short s) {
  return __uint_as_float((unsigned)s << 16);
}

// ---------------------------------------------------------------------------
// 256x256 bf16 GEMM with INLINE-ASM ds_read fragment loads.
//   C = A[16384,1024] @ B[NT_N*256,1024]^T + bias
// Why asm reads: compiler-visible ds_reads against runtime-offset LDS that
// global_load_lds also writes force the backend waitcnt pass to insert
// conservative vmcnt(0) drains every K-half (drain-0 == 1-phase perf, the
// 33% MfmaUtil we measured twice). asm ds_read_b128 is invisible to that
// pass; ALL waits are manual:
//   - vmcnt(8) once per K-half at r1 (retires slot h+1; tail 4->0)  [T4]
//   - lgkmcnt(0)+sched_barrier(0) before each MFMA cluster (rule #18)
//   - raw s_barrier (never __syncthreads -> no forced drain)
// Rhythm per K-half h (2 regions, 2 barriers):
//  r1: lgkm0 | DSR a2(h) | STG A/B(h+3) | MFMA1(h) | vmcnt(8) | bar
//  r2: lgkm0 | DSR bb,a1(h+1)           | MFMA2(h)            | bar
// WAR safety: STG(h+3) writes slot (h-1)&3; all reads of that slot retired
// >=1 barrier earlier (a2(h-1) via lgkm0@r2(h-1) before end-bar(h-1)).
// RAW safety: DSR slot s only after the VMW that retires s's 4 stage-loads.
// Chunk-XOR swizzle (0-conflict, measured): row r's k-chunk c at LDS chunk
// c^((r>>1)&3); read phase fq = (q8^((fr>>1)&3))*8 -> 2-way = free.
// ---------------------------------------------------------------------------
template <int NT_N, int OUT_BF16>
__global__ __launch_bounds__(512, 2) void gemm256(
    const unsigned short* __restrict__ A,
    const unsigned short* __restrict__ B,
    const float* __restrict__ b0, const float* __restrict__ b1,
    const float* __restrict__ b2,
    void* __restrict__ C0, void* __restrict__ C1, void* __restrict__ C2)
{
    __shared__ unsigned short SA[4][8192];   // 4 slots x 256x32 bf16 = 64KB
    __shared__ unsigned short SB[4][8192];   // 64KB  (total 128KB)
    const int t    = threadIdx.x;
    const int lane = t & 63;
    const int w    = t >> 6;

    // bijective XCD swizzle (nwg % 8 == 0 for both grids)
    const int cpx = gridDim.x >> 3;
    const int swz = (blockIdx.x & 7) * cpx + (blockIdx.x >> 3);
    const int mi  = swz / NT_N;
    const int ni  = swz % NT_N;
    const int m0  = mi * 256;
    const int n0g = ni * 256;                    // row into concat B

    const int wm = (w >> 2) * 128;
    const int wn = (w & 3) * 64;

    // staging: thread t -> row t>>2 (+128*j), global k-seg (t&3)^((t>>3)&3)
    // stored at LDS chunk t&3   [(t>>3)&3 == (row>>1)&3, j-independent]
    const int srow = t >> 2;
    const int sseg = ((t & 3) ^ ((t >> 3) & 3)) * 8;
    const unsigned short* Ag = A + (size_t)(m0 + srow) * 1024 + sseg;
    const unsigned short* Bg = B + (size_t)(n0g + srow) * 1024 + sseg;
    const int ldst = w * 512;                    // wave-uniform LDS base

    // fragment read: row fr's k-chunk q8 sits at LDS chunk q8^((fr>>1)&3)
    const int fr = lane & 15;
    const int fq = ((lane >> 4) ^ ((fr >> 1) & 3)) * 8;

    // per-lane LDS byte bases for asm ds_read (compile-time offset: rest)
    const unsigned abase = (unsigned)(size_t)
        (__attribute__((address_space(3))) unsigned short*)&SA[0][0]
        + (unsigned)(((wm + fr) * 32 + fq) * 2);
    const unsigned bbase = (unsigned)(size_t)
        (__attribute__((address_space(3))) unsigned short*)&SB[0][0]
        + (unsigned)(((wn + fr) * 32 + fq) * 2);

    f32x4 acc[8][4] = {};
    bf16x8 a1[4], a2[4], bb[2][4];

#define STGA(k, j)                                                            \
  GLOAD_LDS16(Ag + (size_t)(j) * 131072 + (size_t)(k) * 32,                   \
              &SA[(k) & 3][(j) * 4096 + ldst])
#define STGB(k, j)                                                            \
  GLOAD_LDS16(Bg + (size_t)(j) * 131072 + (size_t)(k) * 32,                   \
              &SB[(k) & 3][(j) * 4096 + ldst])
// asm ds_read_b128: base VGPR + compile-time immediate offset
#define DSR(dst, base, imm)                                                   \
  asm volatile("ds_read_b128 %0, %1 offset:%2"                                \
               : "=v"(dst) : "v"(base), "i"(imm))
#define VMW_(N) asm volatile("s_waitcnt vmcnt(" #N ")" ::: "memory")
#define VMW(N) VMW_(N)
#define LGKM0                                                                 \
  asm volatile("s_waitcnt lgkmcnt(0)" ::: "memory");                          \
  __builtin_amdgcn_sched_barrier(0)
#define BARRIER                                                               \
  __builtin_amdgcn_s_barrier();                                               \
  __builtin_amdgcn_sched_barrier(0)

#define BODY(h, VM, DOSTG, DORD)                                              \
  {                                                                           \
    LGKM0;                                                                    \
    _Pragma("unroll")                                                         \
    for (int mf = 0; mf < 4; ++mf)                                            \
      DSR(a2[mf], abase, ((h) & 3) * 16384 + 4096 + mf * 1024);               \
    if (DOSTG) {                                                              \
      STGA((h) + 3, 0); STGA((h) + 3, 1);                                     \
      STGB((h) + 3, 0); STGB((h) + 3, 1);                                     \
    }                                                                         \
    __builtin_amdgcn_s_setprio(1);                                            \
    _Pragma("unroll")                                                         \
    for (int mf = 0; mf < 4; ++mf)                                            \
      _Pragma("unroll")                                                       \
      for (int nf = 0; nf < 4; ++nf)                                          \
        acc[mf][nf] = __builtin_amdgcn_mfma_f32_16x16x32_bf16(                \
            a1[mf], bb[(h) & 1][nf], acc[mf][nf], 0, 0, 0);                   \
    __builtin_amdgcn_s_setprio(0);                                            \
    VMW(VM);                                                                  \
    BARRIER;                                                                  \
    LGKM0;                                                                    \
    if (DORD) {                                                               \
      _Pragma("unroll")                                                       \
      for (int nf = 0; nf < 4; ++nf)                                          \
        DSR(bb[((h) + 1) & 1][nf], bbase,                                     \
            (((h) + 1) & 3) * 16384 + nf * 1024);                             \
      _Pragma("unroll")                                                       \
      for (int mf = 0; mf < 4; ++mf)                                          \
        DSR(a1[mf], abase, (((h) + 1) & 3) * 16384 + mf * 1024);              \
    }                                                                         \
    __builtin_amdgcn_s_setprio(1);                                            \
    _Pragma("unroll")                                                         \
    for (int mf = 0; mf < 4; ++mf)                                            \
      _Pragma("unroll")                                                       \
      for (int nf = 0; nf < 4; ++nf)                                          \
        acc[4 + mf][nf] = __builtin_amdgcn_mfma_f32_16x16x32_bf16(            \
            a2[mf], bb[(h) & 1][nf], acc[4 + mf][nf], 0, 0, 0);               \
    __builtin_amdgcn_s_setprio(0);                                            \
    BARRIER;                                                                  \
  }

    // ---- prologue: stage K-halves 0,1,2 (12 loads in flight) ----
    STGA(0, 0); STGA(0, 1); STGB(0, 0); STGB(0, 1);
    STGA(1, 0); STGA(1, 1); STGB(1, 0); STGB(1, 1);
    STGA(2, 0); STGA(2, 1); STGB(2, 0); STGB(2, 1);
    VMW(8);               // slot 0 landed
    BARRIER;
#pragma unroll
    for (int nf = 0; nf < 4; ++nf)
        DSR(bb[0][nf], bbase, nf * 1024);
#pragma unroll
    for (int mf = 0; mf < 4; ++mf)
        DSR(a1[mf], abase, mf * 1024);

    // ---- main: 32 K-halves, fully unrolled, compile-time slots ----
    BODY(0, 8, 1, 1)  BODY(1, 8, 1, 1)  BODY(2, 8, 1, 1)  BODY(3, 8, 1, 1)
    BODY(4, 8, 1, 1)  BODY(5, 8, 1, 1)  BODY(6, 8, 1, 1)  BODY(7, 8, 1, 1)
    BODY(8, 8, 1, 1)  BODY(9, 8, 1, 1)  BODY(10, 8, 1, 1) BODY(11, 8, 1, 1)
    BODY(12, 8, 1, 1) BODY(13, 8, 1, 1) BODY(14, 8, 1, 1) BODY(15, 8, 1, 1)
    BODY(16, 8, 1, 1) BODY(17, 8, 1, 1) BODY(18, 8, 1, 1) BODY(19, 8, 1, 1)
    BODY(20, 8, 1, 1) BODY(21, 8, 1, 1) BODY(22, 8, 1, 1) BODY(23, 8, 1, 1)
    BODY(24, 8, 1, 1) BODY(25, 8, 1, 1) BODY(26, 8, 1, 1) BODY(27, 8, 1, 1)
    BODY(28, 8, 1, 1) BODY(29, 4, 0, 1) BODY(30, 0, 0, 1) BODY(31, 0, 0, 0)

#undef BODY
#undef BARRIER
#undef LGKM0
#undef VMW
#undef VMW_
#undef DSR
#undef STGB
#undef STGA

    // epilogue: matrix select (uniform per block); C/D layout col=lane&15,
    // row=(lane>>4)*4+r
    const int mat = ni >> 2;
    const float* bias = (mat == 0) ? b0 : (mat == 1) ? b1 : b2;
    void* Cp = (mat == 0) ? C0 : (mat == 1) ? C1 : C2;
    const int n0 = (ni & 3) * 256;

    const int col = lane & 15;
    const int rq  = (lane >> 4) * 4;
#pragma unroll
    for (int nf = 0; nf < 4; ++nf) {
        int cbase = n0 + wn + nf * 16 + col;
        float bv = bias[cbase];
#pragma unroll
        for (int mf = 0; mf < 8; ++mf) {
            int rbase = m0 + wm + (mf >> 2) * 64 + (mf & 3) * 16 + rq;
#pragma unroll
            for (int r = 0; r < 4; ++r) {
                float val = acc[mf][nf][r] + bv;
                size_t idx = (size_t)(rbase + r) * 1024 + cbase;
                if (OUT_BF16)
                    ((unsigned short*)Cp)[idx] = f2bf(val);
                else
                    ((float*)Cp)[idx] = val;
            }
        }
    }
}

// ---------------------------------------------------------------------------
// fp32 -> bf16 casts
// ---------------------------------------------------------------------------
__global__ __launch_bounds__(256) void cast_bf16(
    const float* __restrict__ src, unsigned short* __restrict__ dst, int n)
{
    int i = (blockIdx.x * 256 + threadIdx.x) * 4;
    if (i >= n) return;
    float4 v = *(const float4*)&src[i];
    ushort2 lo = {f2bf(v.x), f2bf(v.y)};
    ushort2 hi = {f2bf(v.z), f2bf(v.w)};
    *(ushort2*)&dst[i] = lo;
    *(ushort2*)&dst[i + 2] = hi;
}

__global__ __launch_bounds__(256) void cast_bf16_w4(
    const float* __restrict__ s0, const float* __restrict__ s1,
    const float* __restrict__ s2, const float* __restrict__ s3,
    unsigned short* __restrict__ d0, unsigned short* __restrict__ d1,
    unsigned short* __restrict__ d2, unsigned short* __restrict__ d3)
{
    const float* s = (blockIdx.y == 0) ? s0 : (blockIdx.y == 1) ? s1
                    : (blockIdx.y == 2) ? s2 : s3;
    unsigned short* d = (blockIdx.y == 0) ? d0 : (blockIdx.y == 1) ? d1
                       : (blockIdx.y == 2) ? d2 : d3;
    int i = (blockIdx.x * 256 + threadIdx.x) * 4;
    float4 v = *(const float4*)&s[i];
    ushort2 lo = {f2bf(v.x), f2bf(v.y)};
    ushort2 hi = {f2bf(v.z), f2bf(v.w)};
    *(ushort2*)&d[i] = lo;
    *(ushort2*)&d[i + 2] = hi;
}

// ---------------------------------------------------------------------------
// MFMA Performer feature map, in place on bf16 rows of 64.
// ---------------------------------------------------------------------------
__global__ __launch_bounds__(256) void featmap_mfma(
    unsigned short* __restrict__ buf, const float* __restrict__ R)
{
    __shared__ unsigned short Rt[64 * 72];
    const int t = threadIdx.x;
    for (int i = t; i < 4096; i += 256) {
        int n = i >> 6, k = i & 63;
        Rt[n * 72 + k] = f2bf(R[k * 64 + n]);
    }
    __syncthreads();

    const int lane = t & 63;
    const int w = t >> 6;
    const size_t rowbase = (size_t)blockIdx.x * 256 + w * 64;
    const int fr = lane & 15;
    const int fq = (lane >> 4) * 8;

    f32x4 acc[4][4] = {};
    float sqacc[4] = {0.f, 0.f, 0.f, 0.f};

#pragma unroll
    for (int ks = 0; ks < 2; ks++) {
        bf16x8 bfr[4];
#pragma unroll
        for (int nt = 0; nt < 4; nt++)
            bfr[nt] = *(const bf16x8*)&Rt[(nt * 16 + fr) * 72 + ks * 32 + fq];
#pragma unroll
        for (int mt = 0; mt < 4; mt++) {
            bf16x8 a = *(const bf16x8*)
                &buf[(rowbase + mt * 16 + fr) * 64 + ks * 32 + fq];
#pragma unroll
            for (int j = 0; j < 8; j++) {
                float v = bf2f((unsigned short)a[j]);
                sqacc[mt] = fmaf(v, v, sqacc[mt]);
            }
#pragma unroll
            for (int nt = 0; nt < 4; nt++)
                acc[mt][nt] = __builtin_amdgcn_mfma_f32_16x16x32_bf16(
                    a, bfr[nt], acc[mt][nt], 0, 0, 0);
        }
    }
#pragma unroll
    for (int mt = 0; mt < 4; mt++) {
        sqacc[mt] += __shfl_xor(sqacc[mt], 16);
        sqacc[mt] += __shfl_xor(sqacc[mt], 32);
    }

    const int col = lane & 15;
    const int rq  = (lane >> 4) * 4;
#pragma unroll
    for (int mt = 0; mt < 4; mt++) {
#pragma unroll
        for (int r = 0; r < 4; r++) {
            float s = __shfl(sqacc[mt], rq + r);
            size_t row = rowbase + mt * 16 + rq + r;
#pragma unroll
            for (int nt = 0; nt < 4; nt++) {
                float val = acc[mt][nt][r] * 0.125f - s * 0.0078125f;
                buf[row * 64 + nt * 16 + col] = f2bf(__expf(val));
            }
        }
    }
}

// ---------------------------------------------------------------------------
// kv[b,h,m,e] += sum_n k'[n,m] * v[n,e] over a 512-token chunk. bf16 in.
// ---------------------------------------------------------------------------
__global__ __launch_bounds__(256) void kv_accum(
    const unsigned short* __restrict__ kp, const unsigned short* __restrict__ vp,
    float* __restrict__ kv)
{
    __shared__ float Ks[16][68];
    __shared__ float Vs[16][68];
    const int chunk = blockIdx.x;
    const int h = blockIdx.y;
    const int b = blockIdx.z;
    const int t = threadIdx.x;
    const int tx = t & 15, ty = t >> 4;
    float c[4][4] = {};
    const int nbase = b * SEQ + chunk * 512;
    const int nl = t >> 4, seg = t & 15;
    for (int n0 = 0; n0 < 512; n0 += 16) {
        size_t gaddr = (size_t)(nbase + n0 + nl) * DIM + h * 64 + seg * 4;
        ushort4 kq = *(const ushort4*)&kp[gaddr];
        ushort4 vq = *(const ushort4*)&vp[gaddr];
        Ks[nl][seg * 4 + 0] = bf2f(kq.x); Ks[nl][seg * 4 + 1] = bf2f(kq.y);
        Ks[nl][seg * 4 + 2] = bf2f(kq.z); Ks[nl][seg * 4 + 3] = bf2f(kq.w);
        Vs[nl][seg * 4 + 0] = bf2f(vq.x); Vs[nl][seg * 4 + 1] = bf2f(vq.y);
        Vs[nl][seg * 4 + 2] = bf2f(vq.z); Vs[nl][seg * 4 + 3] = bf2f(vq.w);
        __syncthreads();
#pragma unroll
        for (int nn = 0; nn < 16; nn++) {
            float4 a = *(const float4*)&Ks[nn][ty * 4];
            float4 bq = *(const float4*)&Vs[nn][tx * 4];
            float aa[4] = {a.x, a.y, a.z, a.w};
            float bb[4] = {bq.x, bq.y, bq.z, bq.w};
#pragma unroll
            for (int i = 0; i < 4; i++)
#pragma unroll
                for (int j = 0; j < 4; j++)
                    c[i][j] += aa[i] * bb[j];
        }
        __syncthreads();
    }
    float* dst = &kv[(size_t)(b * NH + h) * 64 * 64];
#pragma unroll
    for (int i = 0; i < 4; i++)
#pragma unroll
        for (int j = 0; j < 4; j++)
            atomicAdd(&dst[(ty * 4 + i) * 64 + tx * 4 + j], c[i][j]);
}

// ---------------------------------------------------------------------------
// MFMA attn out: per (b,h), out[n,e] = z[n] * (q'[n,:] @ kv[:,e])
// ---------------------------------------------------------------------------
__global__ __launch_bounds__(256) void attn_out_mfma(
    const unsigned short* __restrict__ qp, const float* __restrict__ kv,
    unsigned short* __restrict__ ob)
{
    __shared__ unsigned short kvT[64 * 72];
    const int t = threadIdx.x;
    const int bh = blockIdx.y;
    const int b = bh >> 4, h = bh & 15;
    const float* kvp = &kv[(size_t)bh * 4096];
    for (int i = t; i < 4096; i += 256) {
        int m = i >> 6, e = i & 63;
        kvT[e * 72 + m] = f2bf(kvp[i]);
    }
    __syncthreads();

    const int lane = t & 63;
    const int w = t >> 6;
    const int rowInSeq = blockIdx.x * 256 + w * 64;
    const int fr = lane & 15;
    const int fq = (lane >> 4) * 8;

    f32x4 acc[4][4] = {};
    float rsum[4] = {0.f, 0.f, 0.f, 0.f};

#pragma unroll
    for (int ks = 0; ks < 2; ks++) {
        bf16x8 bfr[4];
#pragma unroll
        for (int nt = 0; nt < 4; nt++)
            bfr[nt] = *(const bf16x8*)&kvT[(nt * 16 + fr) * 72 + ks * 32 + fq];
#pragma unroll
        for (int mt = 0; mt < 4; mt++) {
            size_t n = (size_t)(b * SEQ + rowInSeq + mt * 16 + fr);
            bf16x8 a = *(const bf16x8*)&qp[n * DIM + h * 64 + ks * 32 + fq];
#pragma unroll
            for (int j = 0; j < 8; j++)
                rsum[mt] += bf2f((unsigned short)a[j]);
#pragma unroll
            for (int nt = 0; nt < 4; nt++)
                acc[mt][nt] = __builtin_amdgcn_mfma_f32_16x16x32_bf16(
                    a, bfr[nt], acc[mt][nt], 0, 0, 0);
        }
    }
#pragma unroll
    for (int mt = 0; mt < 4; mt++) {
        rsum[mt] += __shfl_xor(rsum[mt], 16);
        rsum[mt] += __shfl_xor(rsum[mt], 32);
    }

    const int col = lane & 15;
    const int rq  = (lane >> 4) * 4;
#pragma unroll
    for (int mt = 0; mt < 4; mt++) {
#pragma unroll
        for (int r = 0; r < 4; r++) {
            float s = __shfl(rsum[mt], rq + r);
            float z = 1.f / (s + 1e-8f);
            size_t n = (size_t)(b * SEQ + rowInSeq + mt * 16 + rq + r);
#pragma unroll
            for (int nt = 0; nt < 4; nt++)
                ob[n * DIM + h * 64 + nt * 16 + col] = f2bf(acc[mt][nt][r] * z);
        }
    }
}

extern "C" void kernel_launch(void* const* d_in, const int* in_sizes, int n_in,
                              void* d_out, int out_size, void* d_ws, size_t ws_size,
                              hipStream_t stream) {
    const float* x  = (const float*)d_in[0];
    const float* Wq = (const float*)d_in[1];
    const float* bq = (const float*)d_in[2];
    const float* Wk = (const float*)d_in[3];
    const float* bk = (const float*)d_in[4];
    const float* Wv = (const float*)d_in[5];
    const float* bv = (const float*)d_in[6];
    const float* Wo = (const float*)d_in[7];
    const float* bo = (const float*)d_in[8];
    const float* R  = (const float*)d_in[9];
    float* out = (float*)d_out;

    // workspace — 137 MB. qb/kb contiguous (featmap spans both).
    char* p = (char*)d_ws;
    unsigned short* xb = (unsigned short*)p; p += (size_t)NTOK * DIM * 2;  // 32MB
    unsigned short* qb = (unsigned short*)p; p += (size_t)NTOK * DIM * 2;  // 32MB
    unsigned short* kb = (unsigned short*)p; p += (size_t)NTOK * DIM * 2;  // 32MB
    unsigned short* vb = (unsigned short*)p; p += (size_t)NTOK * DIM * 2;  // 32MB
    float* kvb = (float*)p;                  p += (size_t)BATCH * NH * HD * HD * 4; // 1MB
    unsigned short* wqkv = (unsigned short*)p; p += (size_t)3 * DIM * DIM * 2; // 6MB contig
    unsigned short* wob  = (unsigned short*)p; p += (size_t)DIM * DIM * 2;     // 2MB

    hipMemsetAsync(kvb, 0, (size_t)BATCH * NH * HD * HD * sizeof(float), stream);

    cast_bf16<<<NTOK * DIM / (256 * 4), 256, 0, stream>>>(x, xb, NTOK * DIM);
    cast_bf16_w4<<<dim3(DIM * DIM / (256 * 4), 4), 256, 0, stream>>>(
        Wq, Wk, Wv, Wo,
        wqkv, wqkv + (size_t)DIM * DIM, wqkv + (size_t)2 * DIM * DIM, wob);

    // fused QKV projection: 64 m-tiles x 12 n-tiles = 768 blocks, 512 thr
    gemm256<12, 1><<<768, 512, 0, stream>>>(
        xb, wqkv, bq, bk, bv, qb, kb, vb);

    // feature map over q' and k' in one launch (contiguous rows)
    featmap_mfma<<<2 * NTOK * NH / 256, 256, 0, stream>>>(qb, R);

    kv_accum<<<dim3(8, NH, BATCH), 256, 0, stream>>>(kb, vb, kvb);

    // attn output reuses xb
    attn_out_mfma<<<dim3(SEQ / 256, BATCH * NH), 256, 0, stream>>>(qb, kvb, xb);

    // output projection: 64 x 4 = 256 blocks, fp32 out
    gemm256<4, 0><<<256, 512, 0, stream>>>(
        xb, wob, bo, bo, bo, out, out, out);
}

// Round 5
// 380.693 us; speedup vs baseline: 1.1213x; 1.1006x over previous
//
#include <hip/hip_runtime.h>
#include <math.h>

#define DIM 1024
#define NH 16
#define HD 64
#define BATCH 4
#define SEQ 4096
#define NTOK (BATCH*SEQ)  // 16384

typedef float f32x4 __attribute__((ext_vector_type(4)));
typedef short bf16x8 __attribute__((ext_vector_type(8)));

// LDS dest must be WAVE-UNIFORM base; HW writes base + lane*16B.
#define GLOAD_LDS16(gp, lp)                                                    \
  __builtin_amdgcn_global_load_lds(                                            \
      (const __attribute__((address_space(1))) unsigned int*)(gp),             \
      (__attribute__((address_space(3))) unsigned int*)(lp), 16, 0, 0)

__device__ __forceinline__ unsigned short f2bf(float f) {
  unsigned u = __float_as_uint(f);
  unsigned r = (u + 0x7fffu + ((u >> 16) & 1u)) >> 16;
  return (unsigned short)r;
}
__device__ __forceinline__ float bf2f(unsigned short s) {
  return __uint_as_float((unsigned)s << 16);
}

// ---------------------------------------------------------------------------
// 256x256 bf16 GEMM (inline-asm ds_read schedule, R3) + FUSED Performer
// feature map in the epilogue for q/k blocks.
//   C = A[16384,1024] @ B[NT_N*256,1024]^T + bias ; then (q,k only)
//   out = exp((C@R)/8 - ||C||^2/128) per 64-col head span.
// Fusion works because each wave's 64-col span == one head (wn=(w&3)*64).
// Saves the separate featmap kernel: 128 MB HBM round-trip + a launch.
// K-loop schedule unchanged from R3 (vmcnt(8) counted waits, raw barriers,
// asm ds_read_b128, chunk-XOR swizzle, setprio around MFMA).
// ---------------------------------------------------------------------------
template <int NT_N, int OUT_BF16, int FUSE_FM>
__global__ __launch_bounds__(512, 2) void gemm256(
    const unsigned short* __restrict__ A,
    const unsigned short* __restrict__ B,
    const float* __restrict__ b0, const float* __restrict__ b1,
    const float* __restrict__ b2,
    void* __restrict__ C0, void* __restrict__ C1, void* __restrict__ C2,
    const float* __restrict__ Rg)
{
    // single 128KB LDS pool: K-loop uses [0..32768)=A slots, [32768..65536)=B
    // slots (4 x 8192 shorts each); epilogue reuses it for featmap scratch.
    __shared__ __align__(16) unsigned short LDSU[65536];
    const int t    = threadIdx.x;
    const int lane = t & 63;
    const int w    = t >> 6;

    // bijective XCD swizzle (nwg % 8 == 0 for both grids)
    const int cpx = gridDim.x >> 3;
    const int swz = (blockIdx.x & 7) * cpx + (blockIdx.x >> 3);
    const int mi  = swz / NT_N;
    const int ni  = swz % NT_N;
    const int m0  = mi * 256;
    const int n0g = ni * 256;                    // row into concat B

    const int wm = (w >> 2) * 128;
    const int wn = (w & 3) * 64;

    // staging: thread t -> row t>>2 (+128*j), global k-seg (t&3)^((t>>3)&3)
    // stored at LDS chunk t&3   [(t>>3)&3 == (row>>1)&3, j-independent]
    const int srow = t >> 2;
    const int sseg = ((t & 3) ^ ((t >> 3) & 3)) * 8;
    const unsigned short* Ag = A + (size_t)(m0 + srow) * 1024 + sseg;
    const unsigned short* Bg = B + (size_t)(n0g + srow) * 1024 + sseg;
    const int ldst = w * 512;                    // wave-uniform LDS base

    // fragment read: row fr's k-chunk q8 sits at LDS chunk q8^((fr>>1)&3)
    const int fr = lane & 15;
    const int fq = ((lane >> 4) ^ ((fr >> 1) & 3)) * 8;

    // per-lane LDS byte bases for asm ds_read (compile-time offset: rest)
    const unsigned lbase = (unsigned)(size_t)
        (__attribute__((address_space(3))) unsigned short*)&LDSU[0];
    const unsigned abase = lbase + (unsigned)(((wm + fr) * 32 + fq) * 2);
    const unsigned bbase = lbase + 65536u + (unsigned)(((wn + fr) * 32 + fq) * 2);

    f32x4 acc[8][4] = {};
    bf16x8 a1[4], a2[4], bb[2][4];

#define STGA(k, j)                                                            \
  GLOAD_LDS16(Ag + (size_t)(j) * 131072 + (size_t)(k) * 32,                   \
              &LDSU[((k) & 3) * 8192 + (j) * 4096 + ldst])
#define STGB(k, j)                                                            \
  GLOAD_LDS16(Bg + (size_t)(j) * 131072 + (size_t)(k) * 32,                   \
              &LDSU[32768 + ((k) & 3) * 8192 + (j) * 4096 + ldst])
// asm ds_read_b128: base VGPR + compile-time immediate offset
#define DSR(dst, base, imm)                                                   \
  asm volatile("ds_read_b128 %0, %1 offset:%2"                                \
               : "=v"(dst) : "v"(base), "i"(imm))
#define VMW_(N) asm volatile("s_waitcnt vmcnt(" #N ")" ::: "memory")
#define VMW(N) VMW_(N)
#define LGKM0                                                                 \
  asm volatile("s_waitcnt lgkmcnt(0)" ::: "memory");                          \
  __builtin_amdgcn_sched_barrier(0)
#define BARRIER                                                               \
  __builtin_amdgcn_s_barrier();                                               \
  __builtin_amdgcn_sched_barrier(0)

#define BODY(h, VM, DOSTG, DORD)                                              \
  {                                                                           \
    LGKM0;                                                                    \
    _Pragma("unroll")                                                         \
    for (int mf = 0; mf < 4; ++mf)                                            \
      DSR(a2[mf], abase, ((h) & 3) * 16384 + 4096 + mf * 1024);               \
    if (DOSTG) {                                                              \
      STGA((h) + 3, 0); STGA((h) + 3, 1);                                     \
      STGB((h) + 3, 0); STGB((h) + 3, 1);                                     \
    }                                                                         \
    __builtin_amdgcn_s_setprio(1);                                            \
    _Pragma("unroll")                                                         \
    for (int mf = 0; mf < 4; ++mf)                                            \
      _Pragma("unroll")                                                       \
      for (int nf = 0; nf < 4; ++nf)                                          \
        acc[mf][nf] = __builtin_amdgcn_mfma_f32_16x16x32_bf16(                \
            a1[mf], bb[(h) & 1][nf], acc[mf][nf], 0, 0, 0);                   \
    __builtin_amdgcn_s_setprio(0);                                            \
    VMW(VM);                                                                  \
    BARRIER;                                                                  \
    LGKM0;                                                                    \
    if (DORD) {                                                               \
      _Pragma("unroll")                                                       \
      for (int nf = 0; nf < 4; ++nf)                                          \
        DSR(bb[((h) + 1) & 1][nf], bbase,                                     \
            (((h) + 1) & 3) * 16384 + nf * 1024);                             \
      _Pragma("unroll")                                                       \
      for (int mf = 0; mf < 4; ++mf)                                          \
        DSR(a1[mf], abase, (((h) + 1) & 3) * 16384 + mf * 1024);              \
    }                                                                         \
    __builtin_amdgcn_s_setprio(1);                                            \
    _Pragma("unroll")                                                         \
    for (int mf = 0; mf < 4; ++mf)                                            \
      _Pragma("unroll")                                                       \
      for (int nf = 0; nf < 4; ++nf)                                          \
        acc[4 + mf][nf] = __builtin_amdgcn_mfma_f32_16x16x32_bf16(            \
            a2[mf], bb[(h) & 1][nf], acc[4 + mf][nf], 0, 0, 0);               \
    __builtin_amdgcn_s_setprio(0);                                            \
    BARRIER;                                                                  \
  }

    // ---- prologue: stage K-halves 0,1,2 (12 loads in flight) ----
    STGA(0, 0); STGA(0, 1); STGB(0, 0); STGB(0, 1);
    STGA(1, 0); STGA(1, 1); STGB(1, 0); STGB(1, 1);
    STGA(2, 0); STGA(2, 1); STGB(2, 0); STGB(2, 1);
    VMW(8);               // slot 0 landed
    BARRIER;
#pragma unroll
    for (int nf = 0; nf < 4; ++nf)
        DSR(bb[0][nf], bbase, nf * 1024);
#pragma unroll
    for (int mf = 0; mf < 4; ++mf)
        DSR(a1[mf], abase, mf * 1024);

    // ---- main: 32 K-halves, fully unrolled, compile-time slots ----
    BODY(0, 8, 1, 1)  BODY(1, 8, 1, 1)  BODY(2, 8, 1, 1)  BODY(3, 8, 1, 1)
    BODY(4, 8, 1, 1)  BODY(5, 8, 1, 1)  BODY(6, 8, 1, 1)  BODY(7, 8, 1, 1)
    BODY(8, 8, 1, 1)  BODY(9, 8, 1, 1)  BODY(10, 8, 1, 1) BODY(11, 8, 1, 1)
    BODY(12, 8, 1, 1) BODY(13, 8, 1, 1) BODY(14, 8, 1, 1) BODY(15, 8, 1, 1)
    BODY(16, 8, 1, 1) BODY(17, 8, 1, 1) BODY(18, 8, 1, 1) BODY(19, 8, 1, 1)
    BODY(20, 8, 1, 1) BODY(21, 8, 1, 1) BODY(22, 8, 1, 1) BODY(23, 8, 1, 1)
    BODY(24, 8, 1, 1) BODY(25, 8, 1, 1) BODY(26, 8, 1, 1) BODY(27, 8, 1, 1)
    BODY(28, 8, 1, 1) BODY(29, 4, 0, 1) BODY(30, 0, 0, 1) BODY(31, 0, 0, 0)

#undef BODY
#undef BARRIER
#undef LGKM0
#undef VMW
#undef VMW_
#undef DSR
#undef STGB
#undef STGA

    // matrix select (uniform per block); C/D layout col=lane&15,
    // row=(lane>>4)*4+r
    const int mat = ni >> 2;
    const float* bias = (mat == 0) ? b0 : (mat == 1) ? b1 : b2;
    void* Cp = (mat == 0) ? C0 : (mat == 1) ? C1 : C2;
    const int n0 = (ni & 3) * 256;
    const int col = lane & 15;
    const int rq  = (lane >> 4) * 4;

    if (FUSE_FM && mat < 2) {
        // ---- fused Performer feature map: wave's 64 cols == one head ----
        // stage Rt (transposed R, bf16) at LDSU[36864..41472)
        for (int i = t; i < 4096; i += 512) {
            int n2 = i >> 6, k2 = i & 63;
            LDSU[36864 + n2 * 72 + k2] = f2bf(Rg[k2 * 64 + n2]);
        }
        asm volatile("s_waitcnt lgkmcnt(0)" ::: "memory");
        __builtin_amdgcn_s_barrier();

        unsigned short* wlds = &LDSU[w * 4608];   // wave-private 64x72 bf16
        const int fq0 = (lane >> 4) * 8;          // linear (unswizzled) phase
        const int hcol0 = n0 + wn;                // head col base (64-aligned)
        float bv4[4];
#pragma unroll
        for (int nf = 0; nf < 4; ++nf) bv4[nf] = bias[hcol0 + nf * 16 + col];

#pragma unroll
        for (int p = 0; p < 2; ++p) {             // two 64-row passes
            float s4[4][4];
#pragma unroll
            for (int mfl = 0; mfl < 4; ++mfl)
#pragma unroll
                for (int r = 0; r < 4; ++r) s4[mfl][r] = 0.f;
            // bias-add, row-sq-norm partials, LDS transpose (bf16)
#pragma unroll
            for (int mfl = 0; mfl < 4; ++mfl)
#pragma unroll
                for (int nf = 0; nf < 4; ++nf)
#pragma unroll
                    for (int r = 0; r < 4; ++r) {
                        float val = acc[p * 4 + mfl][nf][r] + bv4[nf];
                        s4[mfl][r] = fmaf(val, val, s4[mfl][r]);
                        wlds[(mfl * 16 + rq + r) * 72 + nf * 16 + col] = f2bf(val);
                    }
            // reduce over the 16 col-lanes of each row group
#pragma unroll
            for (int mfl = 0; mfl < 4; ++mfl)
#pragma unroll
                for (int r = 0; r < 4; ++r) {
                    s4[mfl][r] += __shfl_xor(s4[mfl][r], 1);
                    s4[mfl][r] += __shfl_xor(s4[mfl][r], 2);
                    s4[mfl][r] += __shfl_xor(s4[mfl][r], 4);
                    s4[mfl][r] += __shfl_xor(s4[mfl][r], 8);
                }
            // proj = val @ R  (A-frags from wlds, B-frags from Rt)
            f32x4 pr[4][4] = {};
#pragma unroll
            for (int ks = 0; ks < 2; ++ks) {
                bf16x8 bfr[4];
#pragma unroll
                for (int nt = 0; nt < 4; ++nt)
                    bfr[nt] = *(const bf16x8*)
                        &LDSU[36864 + (nt * 16 + fr) * 72 + ks * 32 + fq0];
#pragma unroll
                for (int mfl = 0; mfl < 4; ++mfl) {
                    bf16x8 af = *(const bf16x8*)
                        &wlds[(mfl * 16 + fr) * 72 + ks * 32 + fq0];
#pragma unroll
                    for (int nt = 0; nt < 4; ++nt)
                        pr[mfl][nt] = __builtin_amdgcn_mfma_f32_16x16x32_bf16(
                            af, bfr[nt], pr[mfl][nt], 0, 0, 0);
                }
            }
            // out = exp(proj/8 - sqnorm/128), store bf16
#pragma unroll
            for (int mfl = 0; mfl < 4; ++mfl)
#pragma unroll
                for (int r = 0; r < 4; ++r) {
                    float ss = s4[mfl][r] * 0.0078125f;
                    size_t row = (size_t)(m0 + wm + p * 64 + mfl * 16 + rq + r);
#pragma unroll
                    for (int nt = 0; nt < 4; ++nt) {
                        float e = __expf(pr[mfl][nt][r] * 0.125f - ss);
                        ((unsigned short*)Cp)[row * 1024 + hcol0 + nt * 16 + col]
                            = f2bf(e);
                    }
                }
            // pass-1 frag reads must retire before pass-2 overwrites wlds
            if (p == 0) asm volatile("s_waitcnt lgkmcnt(0)" ::: "memory");
        }
    } else {
        // ---- plain epilogue (v blocks, O-proj) ----
#pragma unroll
        for (int nf = 0; nf < 4; ++nf) {
            int cbase = n0 + wn + nf * 16 + col;
            float bv = bias[cbase];
#pragma unroll
            for (int mf = 0; mf < 8; ++mf) {
                int rbase = m0 + wm + (mf >> 2) * 64 + (mf & 3) * 16 + rq;
#pragma unroll
                for (int r = 0; r < 4; ++r) {
                    float val = acc[mf][nf][r] + bv;
                    size_t idx = (size_t)(rbase + r) * 1024 + cbase;
                    if (OUT_BF16)
                        ((unsigned short*)Cp)[idx] = f2bf(val);
                    else
                        ((float*)Cp)[idx] = val;
                }
            }
        }
    }
}

// ---------------------------------------------------------------------------
// single fused fp32 -> bf16 cast: x (16M) + Wq/Wk/Wv (->wqkv) + Wo (->wob)
// ---------------------------------------------------------------------------
__global__ __launch_bounds__(256) void cast_all(
    const float* __restrict__ x,  const float* __restrict__ Wq,
    const float* __restrict__ Wk, const float* __restrict__ Wv,
    const float* __restrict__ Wo,
    unsigned short* __restrict__ xb, unsigned short* __restrict__ wqkv,
    unsigned short* __restrict__ wob)
{
    const size_t NX = (size_t)NTOK * DIM;   // 16M
    const size_t NW = (size_t)DIM * DIM;    // 1M
    size_t i = ((size_t)blockIdx.x * 256 + threadIdx.x) * 4;
    const float* s; unsigned short* d; size_t off;
    if (i < NX)               { s = x;  d = xb;             off = i; }
    else if (i < NX + NW)     { s = Wq; d = wqkv;           off = i - NX; }
    else if (i < NX + 2 * NW) { s = Wk; d = wqkv + NW;      off = i - NX - NW; }
    else if (i < NX + 3 * NW) { s = Wv; d = wqkv + 2 * NW;  off = i - NX - 2 * NW; }
    else                      { s = Wo; d = wob;            off = i - NX - 3 * NW; }
    float4 v = *(const float4*)&s[off];
    ushort2 lo = {f2bf(v.x), f2bf(v.y)};
    ushort2 hi = {f2bf(v.z), f2bf(v.w)};
    *(ushort2*)&d[off] = lo;
    *(ushort2*)&d[off + 2] = hi;
}

// ---------------------------------------------------------------------------
// kv[b,h,m,e] += sum_n k'[n,m] * v[n,e] over a 512-token chunk. bf16 in.
// ---------------------------------------------------------------------------
__global__ __launch_bounds__(256) void kv_accum(
    const unsigned short* __restrict__ kp, const unsigned short* __restrict__ vp,
    float* __restrict__ kv)
{
    __shared__ float Ks[16][68];
    __shared__ float Vs[16][68];
    const int chunk = blockIdx.x;
    const int h = blockIdx.y;
    const int b = blockIdx.z;
    const int t = threadIdx.x;
    const int tx = t & 15, ty = t >> 4;
    float c[4][4] = {};
    const int nbase = b * SEQ + chunk * 512;
    const int nl = t >> 4, seg = t & 15;
    for (int n0 = 0; n0 < 512; n0 += 16) {
        size_t gaddr = (size_t)(nbase + n0 + nl) * DIM + h * 64 + seg * 4;
        ushort4 kq = *(const ushort4*)&kp[gaddr];
        ushort4 vq = *(const ushort4*)&vp[gaddr];
        Ks[nl][seg * 4 + 0] = bf2f(kq.x); Ks[nl][seg * 4 + 1] = bf2f(kq.y);
        Ks[nl][seg * 4 + 2] = bf2f(kq.z); Ks[nl][seg * 4 + 3] = bf2f(kq.w);
        Vs[nl][seg * 4 + 0] = bf2f(vq.x); Vs[nl][seg * 4 + 1] = bf2f(vq.y);
        Vs[nl][seg * 4 + 2] = bf2f(vq.z); Vs[nl][seg * 4 + 3] = bf2f(vq.w);
        __syncthreads();
#pragma unroll
        for (int nn = 0; nn < 16; nn++) {
            float4 a = *(const float4*)&Ks[nn][ty * 4];
            float4 bq = *(const float4*)&Vs[nn][tx * 4];
            float aa[4] = {a.x, a.y, a.z, a.w};
            float bb[4] = {bq.x, bq.y, bq.z, bq.w};
#pragma unroll
            for (int i = 0; i < 4; i++)
#pragma unroll
                for (int j = 0; j < 4; j++)
                    c[i][j] += aa[i] * bb[j];
        }
        __syncthreads();
    }
    float* dst = &kv[(size_t)(b * NH + h) * 64 * 64];
#pragma unroll
    for (int i = 0; i < 4; i++)
#pragma unroll
        for (int j = 0; j < 4; j++)
            atomicAdd(&dst[(ty * 4 + i) * 64 + tx * 4 + j], c[i][j]);
}

// ---------------------------------------------------------------------------
// MFMA attn out: per (b,h), out[n,e] = z[n] * (q'[n,:] @ kv[:,e])
// ---------------------------------------------------------------------------
__global__ __launch_bounds__(256) void attn_out_mfma(
    const unsigned short* __restrict__ qp, const float* __restrict__ kv,
    unsigned short* __restrict__ ob)
{
    __shared__ unsigned short kvT[64 * 72];
    const int t = threadIdx.x;
    const int bh = blockIdx.y;
    const int b = bh >> 4, h = bh & 15;
    const float* kvp = &kv[(size_t)bh * 4096];
    for (int i = t; i < 4096; i += 256) {
        int m = i >> 6, e = i & 63;
        kvT[e * 72 + m] = f2bf(kvp[i]);
    }
    __syncthreads();

    const int lane = t & 63;
    const int w = t >> 6;
    const int rowInSeq = blockIdx.x * 256 + w * 64;
    const int fr = lane & 15;
    const int fq = (lane >> 4) * 8;

    f32x4 acc[4][4] = {};
    float rsum[4] = {0.f, 0.f, 0.f, 0.f};

#pragma unroll
    for (int ks = 0; ks < 2; ks++) {
        bf16x8 bfr[4];
#pragma unroll
        for (int nt = 0; nt < 4; nt++)
            bfr[nt] = *(const bf16x8*)&kvT[(nt * 16 + fr) * 72 + ks * 32 + fq];
#pragma unroll
        for (int mt = 0; mt < 4; mt++) {
            size_t n = (size_t)(b * SEQ + rowInSeq + mt * 16 + fr);
            bf16x8 a = *(const bf16x8*)&qp[n * DIM + h * 64 + ks * 32 + fq];
#pragma unroll
            for (int j = 0; j < 8; j++)
                rsum[mt] += bf2f((unsigned short)a[j]);
#pragma unroll
            for (int nt = 0; nt < 4; nt++)
                acc[mt][nt] = __builtin_amdgcn_mfma_f32_16x16x32_bf16(
                    a, bfr[nt], acc[mt][nt], 0, 0, 0);
        }
    }
#pragma unroll
    for (int mt = 0; mt < 4; mt++) {
        rsum[mt] += __shfl_xor(rsum[mt], 16);
        rsum[mt] += __shfl_xor(rsum[mt], 32);
    }

    const int col = lane & 15;
    const int rq  = (lane >> 4) * 4;
#pragma unroll
    for (int mt = 0; mt < 4; mt++) {
#pragma unroll
        for (int r = 0; r < 4; r++) {
            float s = __shfl(rsum[mt], rq + r);
            float z = 1.f / (s + 1e-8f);
            size_t n = (size_t)(b * SEQ + rowInSeq + mt * 16 + rq + r);
#pragma unroll
            for (int nt = 0; nt < 4; nt++)
                ob[n * DIM + h * 64 + nt * 16 + col] = f2bf(acc[mt][nt][r] * z);
        }
    }
}

extern "C" void kernel_launch(void* const* d_in, const int* in_sizes, int n_in,
                              void* d_out, int out_size, void* d_ws, size_t ws_size,
                              hipStream_t stream) {
    const float* x  = (const float*)d_in[0];
    const float* Wq = (const float*)d_in[1];
    const float* bq = (const float*)d_in[2];
    const float* Wk = (const float*)d_in[3];
    const float* bk = (const float*)d_in[4];
    const float* Wv = (const float*)d_in[5];
    const float* bv = (const float*)d_in[6];
    const float* Wo = (const float*)d_in[7];
    const float* bo = (const float*)d_in[8];
    const float* R  = (const float*)d_in[9];
    float* out = (float*)d_out;

    // workspace — 137 MB. qb/kb contiguous.
    char* p = (char*)d_ws;
    unsigned short* xb = (unsigned short*)p; p += (size_t)NTOK * DIM * 2;  // 32MB
    unsigned short* qb = (unsigned short*)p; p += (size_t)NTOK * DIM * 2;  // 32MB
    unsigned short* kb = (unsigned short*)p; p += (size_t)NTOK * DIM * 2;  // 32MB
    unsigned short* vb = (unsigned short*)p; p += (size_t)NTOK * DIM * 2;  // 32MB
    float* kvb = (float*)p;                  p += (size_t)BATCH * NH * HD * HD * 4; // 1MB
    unsigned short* wqkv = (unsigned short*)p; p += (size_t)3 * DIM * DIM * 2; // 6MB contig
    unsigned short* wob  = (unsigned short*)p; p += (size_t)DIM * DIM * 2;     // 2MB

    hipMemsetAsync(kvb, 0, (size_t)BATCH * NH * HD * HD * sizeof(float), stream);

    // single fused cast launch: x + all 4 weight matrices
    cast_all<<<(NTOK * DIM + 4 * DIM * DIM) / (256 * 4), 256, 0, stream>>>(
        x, Wq, Wk, Wv, Wo, xb, wqkv, wob);

    // fused QKV projection + Performer feature map (q,k): 768 blocks
    gemm256<12, 1, 1><<<768, 512, 0, stream>>>(
        xb, wqkv, bq, bk, bv, qb, kb, vb, R);

    kv_accum<<<dim3(8, NH, BATCH), 256, 0, stream>>>(kb, vb, kvb);

    // attn output reuses xb
    attn_out_mfma<<<dim3(SEQ / 256, BATCH * NH), 256, 0, stream>>>(qb, kvb, xb);

    // output projection: 64 x 4 = 256 blocks, fp32 out
    gemm256<4, 0, 0><<<256, 512, 0, stream>>>(
        xb, wob, bo, bo, bo, out, out, out, nullptr);
}